// Round 13
// baseline (19785.922 us; speedup 1.0000x reference)
//
#include <hip/hip_runtime.h>

#define NB 64
#define NT 256
#define ND 1024
#define NH 1024
#define G4 4096

typedef _Float16 half_t;
typedef half_t v8h __attribute__((ext_vector_type(8)));
typedef half_t h4  __attribute__((ext_vector_type(4)));
typedef float  v4f __attribute__((ext_vector_type(4)));

#define XPLANE ((size_t)NB * NT * ND)   // 16,777,216 elems per x plane
#define HPLANE ((size_t)NB * NH)        // 65,536 elems per h plane
#define WREG   16384                    // halves per (combo,jp,gt,kh) region (32 KB)

// ---- one-time: x (f32, B,T,D) -> fp16 hi/lo planes, transposed to [t][b][d] ----
__global__ void cvt_x(const float* __restrict__ x,
                      half_t* __restrict__ xh, half_t* __restrict__ xl) {
    const int row = blockIdx.x;             // row = b*256 + t
    const int b = row >> 8, t = row & 255;
    const int o = threadIdx.x * 4;
    const float4 v = *(const float4*)(x + (size_t)row * ND + o);
    const size_t d = ((size_t)t * NB + b) * ND + o;
    h4 hh, ll;
    hh.x = (half_t)v.x; ll.x = (half_t)(v.x - (float)hh.x);
    hh.y = (half_t)v.y; ll.y = (half_t)(v.y - (float)hh.y);
    hh.z = (half_t)v.z; ll.z = (half_t)(v.z - (float)hh.z);
    hh.w = (half_t)v.w; ll.w = (half_t)(v.w - (float)hh.w);
    *(h4*)(xh + d) = hh;
    *(h4*)(xl + d) = ll;
}

// ---- one-time weight pack: fp16, region per (combo,jp,gt,kh): [ki 0..31][lane][8] ----
__global__ void transpose_pack(const float* __restrict__ fw_Wx,
                               const float* __restrict__ fw_Wh,
                               const float* __restrict__ bw_Wx,
                               const float* __restrict__ bw_Wh,
                               half_t* __restrict__ WT) {
    const int z = blockIdx.z;
    const int combo = z >> 1;
    const int half  = z & 1;               // 0 -> Wx, 1 -> Wh (== kh)
    const int layer = combo >> 1, dirb = combo & 1;
    const float* src = half ? (dirb ? bw_Wh : fw_Wh) : (dirb ? bw_Wx : fw_Wx);
    src += (size_t)layer * ND * G4;
    const int n0 = blockIdx.x * 64, k0 = blockIdx.y * 64;
    __shared__ float tile[64][65];
    const int t = threadIdx.x;             // 256 threads
    #pragma unroll
    for (int it = 0; it < 4; ++it) {
        const int kr = it * 16 + (t >> 4);
        const int nc = (t & 15) * 4;
        const float4 v = *(const float4*)(src + (size_t)(k0 + kr) * G4 + n0 + nc);
        tile[kr][nc + 0] = v.x; tile[kr][nc + 1] = v.y;
        tile[kr][nc + 2] = v.z; tile[kr][nc + 3] = v.w;
    }
    __syncthreads();
    #pragma unroll
    for (int it = 0; it < 4; ++it) {
        const int nr = it * 16 + (t >> 4);
        const int kc = (t & 15) * 4;
        h4 hv;
        hv.x = (half_t)tile[kc + 0][nr];
        hv.y = (half_t)tile[kc + 1][nr];
        hv.z = (half_t)tile[kc + 2][nr];
        hv.w = (half_t)tile[kc + 3][nr];
        const int n = n0 + nr;                 // 0..4095
        const int kr1 = k0 + kc;               // 0..1023 within this kh
        const int gt = n >> 10, j = n & 1023;
        const int jp = j >> 4, l15j = j & 15;
        const int ki = kr1 >> 5, g2 = (kr1 >> 3) & 3, e0 = kr1 & 7;
        const int lane2 = g2 * 16 + l15j;
        const size_t r = (((size_t)combo * 64 + jp) * 4 + gt) * 2 + half;
        *(h4*)(WT + r * WREG + (size_t)ki * 512 + lane2 * 8 + e0) = hv;
    }
}

// ---- sc1 store (write-through past the non-coherent L2) ----
__device__ __forceinline__ void store_h2(half_t* p, half_t a, half_t b) {
    union { half_t h[2]; unsigned int u; } v;
    v.h[0] = a; v.h[1] = b;
    __hip_atomic_store((unsigned int*)p, v.u,
                       __ATOMIC_RELAXED, __HIP_MEMORY_SCOPE_AGENT);
}

// ---- GEMM half: M=64, N=16, K=1024 over one hi/lo plane-pair, W from AGPRs ----
__device__ __forceinline__ void gemm_half(const half_t* __restrict__ Ah,
                                          const half_t* __restrict__ Al,
                                          const v8h w[32],
                                          v4f* __restrict__ acc,
                                          int arow) {
    #pragma unroll 4
    for (int ki = 0; ki < 32; ++ki) {
        const int off = arow + ki * 32;
        #pragma unroll
        for (int m = 0; m < 4; ++m) {
            v8h ah = *(const v8h*)(Ah + off + m * 16384);
            v8h al = *(const v8h*)(Al + off + m * 16384);
            acc[m] = __builtin_amdgcn_mfma_f32_16x16x32_f16(ah, w[ki], acc[m], 0, 0, 0);
            acc[m] = __builtin_amdgcn_mfma_f32_16x16x32_f16(al, w[ki], acc[m], 0, 0, 0);
        }
    }
}

// ---- persistent scan: 256 blocks x 512 thr; 8 waves = (gate, khalf) ----
// XCD-aware mapping: combo c -> XCDs {2c, 2c+1} (assumes bid%8 XCD round-robin;
// wrong assumption = perf-neutral, never incorrect).
// hring: [slot 0..NT][combo][plane hi/lo][B][H] fp16 — monotonic, write-once addresses
__global__ __launch_bounds__(512, 2) void lstm_persistent(
        const half_t* __restrict__ xh, const half_t* __restrict__ xl,
        const int* __restrict__ lengths,
        const float* __restrict__ fw_b, const float* __restrict__ bw_b,
        const half_t* __restrict__ WT,
        half_t* __restrict__ hring,
        float* __restrict__ out,
        int* __restrict__ bar) {
    const int bid = blockIdx.x;
    const int c  = (bid & 7) >> 1;              // combo: XCD-pair-local
    const int jp = ((bid >> 3) << 1) | (bid & 1);   // 0..63
    const int layer = c >> 1, dir = c & 1;
    const int tid = threadIdx.x;
    const int wv = tid >> 6, lane = tid & 63;
    const int gt = wv & 3, kh = wv >> 2;   // gate, K-half (1024 wide)
    const int l15 = lane & 15, g = lane >> 4;
    const int j0 = jp * 16;
    const int arow = l15 * 1024 + g * 8;   // A base offset (row l15, k g*8)

    __shared__ float glds[4][2][NB][16];   // 32 KB
    __shared__ float c_lds[NB][16];
    __shared__ float h_lds[NB][16];
    __shared__ float bias_lds[4][16];
    __shared__ int   len_lds[NB];

    for (int e = tid; e < NB * 16; e += 512) {
        c_lds[e >> 4][e & 15] = 0.f;
        h_lds[e >> 4][e & 15] = 0.f;
    }
    if (tid < NB) len_lds[tid] = lengths[tid];
    if (tid < 64) {
        const int gg = tid >> 4, jj = tid & 15;
        const float* bs = dir ? bw_b : fw_b;
        bias_lds[gg][jj] = bs[(size_t)layer * G4 + gg * NH + j0 + jj];
    }

    // ---- weight preload, then pin ONCE into AGPRs ----
    v8h w[32];
    {
        const half_t* wp = WT + ((((size_t)c * 64 + jp) * 4 + gt) * 2 + kh) * WREG
                         + (size_t)lane * 8;
        #pragma unroll
        for (int ki = 0; ki < 32; ++ki) w[ki] = *(const v8h*)(wp + (size_t)ki * 512);
    }
    #pragma unroll
    for (int ki = 0; ki < 32; ++ki) asm volatile("" : "+a"(w[ki]));  // once, pre-loop
    __syncthreads();

    // barrier bookkeeping: per-direction, 8 groups of 16 blocks, monotonic phases
    const int id128 = layer * 64 + jp;         // 0..127 within direction
    int* gcnt = bar + ((size_t)dir * 8 + (id128 >> 4)) * 16;
    int* root = bar + 256 + dir * 16;
    int* rel  = bar + 320 + dir * 16;

    for (int s = 0; s <= NT; ++s) {
        const bool active = (layer == 0) ? (s < NT) : (s >= 1);
        const int u = (layer == 0) ? s : (s - 1);

        if (active) {
            // A sources (normal cached loads; all 32 blocks of this XCD read the
            // SAME lines -> one L2 fill serves the whole XCD)
            const half_t *Ah, *Al;
            if (kh == 0) {
                if (layer == 0) {
                    const int t = dir ? (NT - 1 - u) : u;
                    Ah = xh + (size_t)t * NB * ND;
                    Al = xl + (size_t)t * NB * ND;
                } else {
                    // layer-0 (same dir) output after its step s-1 lives in slot s
                    const half_t* hb = hring + (((size_t)s * 4 + dir) * 2) * HPLANE;
                    Ah = hb; Al = hb + HPLANE;
                }
            } else {
                // own recurrent state: slot u
                const half_t* hb = hring + (((size_t)u * 4 + c) * 2) * HPLANE;
                Ah = hb; Al = hb + HPLANE;
            }

            v4f acc[4];
            #pragma unroll
            for (int m = 0; m < 4; ++m) acc[m] = (v4f){0.f, 0.f, 0.f, 0.f};
            gemm_half(Ah, Al, w, acc, arow);

            // C/D: col = l15 (jj), row-in-Mtile = g*4 + r (batch)
            #pragma unroll
            for (int m = 0; m < 4; ++m)
                #pragma unroll
                for (int r = 0; r < 4; ++r)
                    glds[gt][kh][m * 16 + g * 4 + r][l15] = acc[m][r];
        }
        __syncthreads();

        if (active) {
            // 512 threads, 1024 cells: each handles (b, jj0) and (b, jj0+1)
            const int b = tid >> 3, jj0 = (tid & 7) * 2;
            float hpair[2];
            #pragma unroll
            for (int k2 = 0; k2 < 2; ++k2) {
                const int jj = jj0 + k2;
                const float iv = glds[0][0][b][jj] + glds[0][1][b][jj] + bias_lds[0][jj];
                const float fv = glds[1][0][b][jj] + glds[1][1][b][jj] + bias_lds[1][jj];
                const float gv = glds[2][0][b][jj] + glds[2][1][b][jj] + bias_lds[2][jj];
                const float ov = glds[3][0][b][jj] + glds[3][1][b][jj] + bias_lds[3][jj];
                const float cold = c_lds[b][jj];
                const float hold = h_lds[b][jj];
                const float si = 1.f / (1.f + expf(-iv));
                const float sf = 1.f / (1.f + expf(-fv));
                const float so = 1.f / (1.f + expf(-ov));
                const float cn = sf * cold + si * tanhf(gv);
                const float hn = so * tanhf(cn);
                const bool valid = len_lds[b] > u;   // un-reversed mask (reference quirk)
                const float c2 = valid ? cn : cold;
                const float h2 = valid ? hn : hold;
                c_lds[b][jj] = c2;
                h_lds[b][jj] = h2;
                hpair[k2] = h2;
                if (layer == 1) {
                    const int tout = dir ? (NT - 1 - u) : u;
                    __builtin_nontemporal_store(
                        h2, &out[((size_t)b * NT + tout) * (2 * NH) + dir * NH + j0 + jj]);
                    if (u == NT - 1)
                        __builtin_nontemporal_store(
                            h2, &out[(size_t)NB * NT * (2 * NH) + (size_t)b * (2 * NH)
                                     + dir * NH + j0 + jj]);
                }
            }
            // h handoff into fresh ring slot u+1 via sc1 write-through stores
            half_t* hb = hring + (((size_t)(u + 1) * 4 + c) * 2) * HPLANE
                       + (size_t)b * NH + j0 + jj0;
            const half_t h0 = (half_t)hpair[0], h1 = (half_t)hpair[1];
            store_h2(hb, h0, h1);
            store_h2(hb + HPLANE, (half_t)(hpair[0] - (float)h0),
                                  (half_t)(hpair[1] - (float)h1));
        }

        // ---- per-direction barrier: relaxed atomics, NO fences, NO invalidates ----
        const int phase = s + 1;
        __syncthreads();                    // vmcnt(0) drain: sc1 h-stores visible
        if (tid == 0) {
            const int a = __hip_atomic_fetch_add(gcnt, 1, __ATOMIC_RELAXED,
                                                 __HIP_MEMORY_SCOPE_AGENT) + 1;
            if (a == phase * 16) {
                const int rr = __hip_atomic_fetch_add(root, 1, __ATOMIC_RELAXED,
                                                      __HIP_MEMORY_SCOPE_AGENT) + 1;
                if (rr == phase * 8)
                    __hip_atomic_store(rel, phase, __ATOMIC_RELAXED,
                                       __HIP_MEMORY_SCOPE_AGENT);
            }
            while (__hip_atomic_load(rel, __ATOMIC_RELAXED,
                                     __HIP_MEMORY_SCOPE_AGENT) < phase)
                __builtin_amdgcn_s_sleep(2);
        }
        __syncthreads();
    }
}

extern "C" void kernel_launch(void* const* d_in, const int* in_sizes, int n_in,
                              void* d_out, int out_size, void* d_ws, size_t ws_size,
                              hipStream_t stream) {
    (void)in_sizes; (void)n_in; (void)out_size; (void)ws_size;
    const float* x     = (const float*)d_in[0];
    const int*   len   = (const int*)d_in[1];
    const float* fw_Wx = (const float*)d_in[2];
    const float* fw_Wh = (const float*)d_in[3];
    const float* fw_b  = (const float*)d_in[4];
    const float* bw_Wx = (const float*)d_in[5];
    const float* bw_Wh = (const float*)d_in[6];
    const float* bw_b  = (const float*)d_in[7];
    float* out = (float*)d_out;

    char* ws = (char*)d_ws;
    size_t off = 0;
    half_t* WT = (half_t*)(ws + off); off += (size_t)2048 * WREG * 2;   // 64 MB
    half_t* xh = (half_t*)(ws + off); off += XPLANE * 2;                // 32 MB
    half_t* xl = (half_t*)(ws + off); off += XPLANE * 2;                // 32 MB
    int* bar = (int*)(ws + off); off += 4096;                           // 4 KB
    half_t* hring = (half_t*)(ws + off);                                // 257 MB

    // zero barrier counters + ring slot 0 (4 combos x 2 planes x 128 KB = 1 MB)
    hipMemsetAsync(bar, 0, 4096 + (size_t)4 * 2 * HPLANE * 2, stream);

    cvt_x<<<NB * NT, 256, 0, stream>>>(x, xh, xl);

    dim3 tg(G4 / 64, ND / 64, 8);
    transpose_pack<<<tg, 256, 0, stream>>>(fw_Wx, fw_Wh, bw_Wx, bw_Wh, WT);

    void* args[] = {(void*)&xh, (void*)&xl, (void*)&len, (void*)&fw_b,
                    (void*)&bw_b, (void*)&WT, (void*)&hring, (void*)&out,
                    (void*)&bar};
    hipLaunchCooperativeKernel((void*)lstm_persistent, dim3(256), dim3(512),
                               args, 0, stream);
}

// Round 14
// 5395.364 us; speedup vs baseline: 3.6672x; 3.6672x over previous
//
#include <hip/hip_runtime.h>

#define NB 64
#define NT 256
#define ND 1024
#define NH 1024
#define G4 4096

typedef _Float16 half_t;
typedef half_t v8h __attribute__((ext_vector_type(8)));
typedef half_t h4  __attribute__((ext_vector_type(4)));
typedef float  v4f __attribute__((ext_vector_type(4)));

#define XPLANE ((size_t)NB * NT * ND)
#define HPLANE ((size_t)NB * NH)
#define WREG   16384                    // halves per (combo,jp,gt,kh) region (32 KB)

// ---- one-time: x (f32, B,T,D) -> fp16 hi/lo planes, transposed to [t][b][d] ----
__global__ void cvt_x(const float* __restrict__ x,
                      half_t* __restrict__ xh, half_t* __restrict__ xl) {
    const int row = blockIdx.x;             // row = b*256 + t
    const int b = row >> 8, t = row & 255;
    const int o = threadIdx.x * 4;
    const float4 v = *(const float4*)(x + (size_t)row * ND + o);
    const size_t d = ((size_t)t * NB + b) * ND + o;
    h4 hh, ll;
    hh.x = (half_t)v.x; ll.x = (half_t)(v.x - (float)hh.x);
    hh.y = (half_t)v.y; ll.y = (half_t)(v.y - (float)hh.y);
    hh.z = (half_t)v.z; ll.z = (half_t)(v.z - (float)hh.z);
    hh.w = (half_t)v.w; ll.w = (half_t)(v.w - (float)hh.w);
    *(h4*)(xh + d) = hh;
    *(h4*)(xl + d) = ll;
}

// ---- one-time weight pack: fp16, region per (combo,jp,gt,kh): [ki 0..31][lane][8] ----
__global__ void transpose_pack(const float* __restrict__ fw_Wx,
                               const float* __restrict__ fw_Wh,
                               const float* __restrict__ bw_Wx,
                               const float* __restrict__ bw_Wh,
                               half_t* __restrict__ WT) {
    const int z = blockIdx.z;
    const int combo = z >> 1;
    const int half  = z & 1;               // 0 -> Wx, 1 -> Wh (== kh)
    const int layer = combo >> 1, dirb = combo & 1;
    const float* src = half ? (dirb ? bw_Wh : fw_Wh) : (dirb ? bw_Wx : fw_Wx);
    src += (size_t)layer * ND * G4;
    const int n0 = blockIdx.x * 64, k0 = blockIdx.y * 64;
    __shared__ float tile[64][65];
    const int t = threadIdx.x;             // 256 threads
    #pragma unroll
    for (int it = 0; it < 4; ++it) {
        const int kr = it * 16 + (t >> 4);
        const int nc = (t & 15) * 4;
        const float4 v = *(const float4*)(src + (size_t)(k0 + kr) * G4 + n0 + nc);
        tile[kr][nc + 0] = v.x; tile[kr][nc + 1] = v.y;
        tile[kr][nc + 2] = v.z; tile[kr][nc + 3] = v.w;
    }
    __syncthreads();
    #pragma unroll
    for (int it = 0; it < 4; ++it) {
        const int nr = it * 16 + (t >> 4);
        const int kc = (t & 15) * 4;
        h4 hv;
        hv.x = (half_t)tile[kc + 0][nr];
        hv.y = (half_t)tile[kc + 1][nr];
        hv.z = (half_t)tile[kc + 2][nr];
        hv.w = (half_t)tile[kc + 3][nr];
        const int n = n0 + nr;
        const int kr1 = k0 + kc;
        const int gt = n >> 10, j = n & 1023;
        const int jp = j >> 4, l15j = j & 15;
        const int ki = kr1 >> 5, g2 = (kr1 >> 3) & 3, e0 = kr1 & 7;
        const int lane2 = g2 * 16 + l15j;
        const size_t r = (((size_t)combo * 64 + jp) * 4 + gt) * 2 + half;
        *(h4*)(WT + r * WREG + (size_t)ki * 512 + lane2 * 8 + e0) = hv;
    }
}

// ---- sc1 store (write-through past the non-coherent L2) ----
__device__ __forceinline__ void store_h2(half_t* p, half_t a, half_t b) {
    union { half_t h[2]; unsigned int u; } v;
    v.h[0] = a; v.h[1] = b;
    __hip_atomic_store((unsigned int*)p, v.u,
                       __ATOMIC_RELAXED, __HIP_MEMORY_SCOPE_AGENT);
}

// ---- persistent scan: 256 blocks x 512 thr; 8 waves = (gate, khalf) ----
// A staged in LDS per K-chunk (128 halves per kh-half) -> global A read ONCE/block.
__global__ __launch_bounds__(512, 2) void lstm_persistent(
        const half_t* __restrict__ xh, const half_t* __restrict__ xl,
        const int* __restrict__ lengths,
        const float* __restrict__ fw_b, const float* __restrict__ bw_b,
        const half_t* __restrict__ WT,
        half_t* __restrict__ hring,
        float* __restrict__ out,
        int* __restrict__ bar) {
    const int bid = blockIdx.x;
    const int c  = (bid & 7) >> 1;                 // combo (XCD-pair-local)
    const int jp = ((bid >> 3) << 1) | (bid & 1);  // 0..63
    const int layer = c >> 1, dir = c & 1;
    const int tid = threadIdx.x;
    const int wv = tid >> 6, lane = tid & 63;
    const int gt = wv & 3, kh = wv >> 2;           // gate, K-half
    const int l15 = lane & 15, g = lane >> 4;
    const int j0 = jp * 16;

    // staging role: 256 threads per kh-half; 4 threads per row
    const int shf  = tid >> 8;                     // which K-half this thread stages
    const int srow = (tid & 255) >> 2;             // 0..63 (batch row)
    const int sks  = (tid & 3) * 32;               // 32-half segment within 128

    __shared__ half_t alds[2][2][64][136];         // [kh][plane][row][128+8 pad] 69.6 KB
    __shared__ float glds[4][2][NB][16];           // 32 KB
    __shared__ float c_lds[NB][16];
    __shared__ float h_lds[NB][16];
    __shared__ float bias_lds[4][16];
    __shared__ int   len_lds[NB];

    for (int e = tid; e < NB * 16; e += 512) {
        c_lds[e >> 4][e & 15] = 0.f;
        h_lds[e >> 4][e & 15] = 0.f;
    }
    if (tid < NB) len_lds[tid] = lengths[tid];
    if (tid < 64) {
        const int gg = tid >> 4, jj = tid & 15;
        const float* bs = dir ? bw_b : fw_b;
        bias_lds[gg][jj] = bs[(size_t)layer * G4 + gg * NH + j0 + jj];
    }

    // ---- weight preload, pinned ONCE into AGPRs ----
    v8h w[32];
    {
        const half_t* wp = WT + ((((size_t)c * 64 + jp) * 4 + gt) * 2 + kh) * WREG
                         + (size_t)lane * 8;
        #pragma unroll
        for (int ki = 0; ki < 32; ++ki) w[ki] = *(const v8h*)(wp + (size_t)ki * 512);
    }
    #pragma unroll
    for (int ki = 0; ki < 32; ++ki) asm volatile("" : "+a"(w[ki]));
    __syncthreads();

    const int id128 = layer * 64 + jp;
    int* gcnt = bar + ((size_t)dir * 8 + (id128 >> 4)) * 16;
    int* root = bar + 256 + dir * 16;
    int* rel  = bar + 320 + dir * 16;

    for (int s = 0; s <= NT; ++s) {
        const bool active = (layer == 0) ? (s < NT) : (s >= 1);
        const int u = (layer == 0) ? s : (s - 1);

        // per-step A bases (uniform): input half + recurrent half, row stride 1024
        const half_t *bh = nullptr, *bl = nullptr;
        if (active) {
            if (shf == 0) {
                if (layer == 0) {
                    const int t = dir ? (NT - 1 - u) : u;
                    bh = xh + (size_t)t * NB * ND;
                    bl = xl + (size_t)t * NB * ND;
                } else {
                    const half_t* hb = hring + (((size_t)s * 4 + dir) * 2) * HPLANE;
                    bh = hb; bl = hb + HPLANE;
                }
            } else {
                const half_t* hb = hring + (((size_t)u * 4 + c) * 2) * HPLANE;
                bh = hb; bl = hb + HPLANE;
            }
        }

        v4f acc[4];
        #pragma unroll
        for (int m = 0; m < 4; ++m) acc[m] = (v4f){0.f, 0.f, 0.f, 0.f};

        v8h sh[4], sl[4];                     // staged regs for current chunk
        if (active) {
            const size_t o0 = (size_t)srow * 1024 + sks;   // chunk 0
            #pragma unroll
            for (int i = 0; i < 4; ++i) {
                sh[i] = *(const v8h*)(bh + o0 + i * 8);
                sl[i] = *(const v8h*)(bl + o0 + i * 8);
            }
        }

        #pragma unroll
        for (int ci = 0; ci < 8; ++ci) {
            __syncthreads();                  // previous chunk fully consumed
            if (active) {
                #pragma unroll
                for (int i = 0; i < 4; ++i) {
                    *(v8h*)&alds[shf][0][srow][sks + i * 8] = sh[i];
                    *(v8h*)&alds[shf][1][srow][sks + i * 8] = sl[i];
                }
            }
            __syncthreads();                  // chunk visible in LDS
            if (active) {
                if (ci < 7) {                 // prefetch next chunk into regs
                    const size_t o = (size_t)srow * 1024 + (ci + 1) * 128 + sks;
                    #pragma unroll
                    for (int i = 0; i < 4; ++i) {
                        sh[i] = *(const v8h*)(bh + o + i * 8);
                        sl[i] = *(const v8h*)(bl + o + i * 8);
                    }
                }
                #pragma unroll
                for (int ki = 0; ki < 4; ++ki) {
                    #pragma unroll
                    for (int m = 0; m < 4; ++m) {
                        const int row = m * 16 + l15;
                        const int ko = ki * 32 + g * 8;
                        v8h ah = *(const v8h*)&alds[kh][0][row][ko];
                        v8h al = *(const v8h*)&alds[kh][1][row][ko];
                        acc[m] = __builtin_amdgcn_mfma_f32_16x16x32_f16(
                                     ah, w[ci * 4 + ki], acc[m], 0, 0, 0);
                        acc[m] = __builtin_amdgcn_mfma_f32_16x16x32_f16(
                                     al, w[ci * 4 + ki], acc[m], 0, 0, 0);
                    }
                }
            }
        }

        if (active) {
            #pragma unroll
            for (int m = 0; m < 4; ++m)
                #pragma unroll
                for (int r = 0; r < 4; ++r)
                    glds[gt][kh][m * 16 + g * 4 + r][l15] = acc[m][r];
        }
        __syncthreads();

        if (active) {
            const int b = tid >> 3, jj0 = (tid & 7) * 2;
            float hpair[2];
            #pragma unroll
            for (int k2 = 0; k2 < 2; ++k2) {
                const int jj = jj0 + k2;
                const float iv = glds[0][0][b][jj] + glds[0][1][b][jj] + bias_lds[0][jj];
                const float fv = glds[1][0][b][jj] + glds[1][1][b][jj] + bias_lds[1][jj];
                const float gv = glds[2][0][b][jj] + glds[2][1][b][jj] + bias_lds[2][jj];
                const float ov = glds[3][0][b][jj] + glds[3][1][b][jj] + bias_lds[3][jj];
                const float cold = c_lds[b][jj];
                const float hold = h_lds[b][jj];
                const float si = 1.f / (1.f + expf(-iv));
                const float sf = 1.f / (1.f + expf(-fv));
                const float so = 1.f / (1.f + expf(-ov));
                const float cn = sf * cold + si * tanhf(gv);
                const float hn = so * tanhf(cn);
                const bool valid = len_lds[b] > u;   // un-reversed mask (reference quirk)
                const float c2 = valid ? cn : cold;
                const float h2 = valid ? hn : hold;
                c_lds[b][jj] = c2;
                h_lds[b][jj] = h2;
                hpair[k2] = h2;
                if (layer == 1) {
                    const int tout = dir ? (NT - 1 - u) : u;
                    __builtin_nontemporal_store(
                        h2, &out[((size_t)b * NT + tout) * (2 * NH) + dir * NH + j0 + jj]);
                    if (u == NT - 1)
                        __builtin_nontemporal_store(
                            h2, &out[(size_t)NB * NT * (2 * NH) + (size_t)b * (2 * NH)
                                     + dir * NH + j0 + jj]);
                }
            }
            half_t* hb2 = hring + (((size_t)(u + 1) * 4 + c) * 2) * HPLANE
                        + (size_t)b * NH + j0 + jj0;
            const half_t h0 = (half_t)hpair[0], h1 = (half_t)hpair[1];
            store_h2(hb2, h0, h1);
            store_h2(hb2 + HPLANE, (half_t)(hpair[0] - (float)h0),
                                   (half_t)(hpair[1] - (float)h1));
        }

        // ---- per-direction barrier: relaxed atomics, no fences ----
        const int phase = s + 1;
        __syncthreads();                    // vmcnt(0): sc1 h-stores visible
        if (tid == 0) {
            const int a = __hip_atomic_fetch_add(gcnt, 1, __ATOMIC_RELAXED,
                                                 __HIP_MEMORY_SCOPE_AGENT) + 1;
            if (a == phase * 16) {
                const int rr = __hip_atomic_fetch_add(root, 1, __ATOMIC_RELAXED,
                                                      __HIP_MEMORY_SCOPE_AGENT) + 1;
                if (rr == phase * 8)
                    __hip_atomic_store(rel, phase, __ATOMIC_RELAXED,
                                       __HIP_MEMORY_SCOPE_AGENT);
            }
            while (__hip_atomic_load(rel, __ATOMIC_RELAXED,
                                     __HIP_MEMORY_SCOPE_AGENT) < phase)
                __builtin_amdgcn_s_sleep(2);
        }
        __syncthreads();
    }
}

extern "C" void kernel_launch(void* const* d_in, const int* in_sizes, int n_in,
                              void* d_out, int out_size, void* d_ws, size_t ws_size,
                              hipStream_t stream) {
    (void)in_sizes; (void)n_in; (void)out_size; (void)ws_size;
    const float* x     = (const float*)d_in[0];
    const int*   len   = (const int*)d_in[1];
    const float* fw_Wx = (const float*)d_in[2];
    const float* fw_Wh = (const float*)d_in[3];
    const float* fw_b  = (const float*)d_in[4];
    const float* bw_Wx = (const float*)d_in[5];
    const float* bw_Wh = (const float*)d_in[6];
    const float* bw_b  = (const float*)d_in[7];
    float* out = (float*)d_out;

    char* ws = (char*)d_ws;
    size_t off = 0;
    half_t* WT = (half_t*)(ws + off); off += (size_t)2048 * WREG * 2;   // 64 MB
    half_t* xh = (half_t*)(ws + off); off += XPLANE * 2;                // 32 MB
    half_t* xl = (half_t*)(ws + off); off += XPLANE * 2;                // 32 MB
    int* bar = (int*)(ws + off); off += 4096;                           // 4 KB
    half_t* hring = (half_t*)(ws + off);                                // 257 MB

    hipMemsetAsync(bar, 0, 4096 + (size_t)4 * 2 * HPLANE * 2, stream);

    cvt_x<<<NB * NT, 256, 0, stream>>>(x, xh, xl);

    dim3 tg(G4 / 64, ND / 64, 8);
    transpose_pack<<<tg, 256, 0, stream>>>(fw_Wx, fw_Wh, bw_Wx, bw_Wh, WT);

    void* args[] = {(void*)&xh, (void*)&xl, (void*)&len, (void*)&fw_b,
                    (void*)&bw_b, (void*)&WT, (void*)&hring, (void*)&out,
                    (void*)&bar};
    hipLaunchCooperativeKernel((void*)lstm_persistent, dim3(256), dim3(512),
                               args, 0, stream);
}

// Round 16
// 2474.958 us; speedup vs baseline: 7.9944x; 2.1800x over previous
//
#include <hip/hip_runtime.h>

#define NB 64
#define NT 256
#define ND 1024
#define NH 1024
#define G4 4096

typedef _Float16 half_t;
typedef half_t v8h __attribute__((ext_vector_type(8)));
typedef half_t h4  __attribute__((ext_vector_type(4)));
typedef float  v4f __attribute__((ext_vector_type(4)));

#define XPLANE ((size_t)NB * NT * ND)
#define HPLANE ((size_t)NB * NH)       // halves per (slot, combo) — single plane
#define WREG   16384                   // halves per (combo,jp,gt,kh) region (32 KB)

// ---- one-time: x (f32, B,T,D) -> fp16 single plane, transposed to [t][b][d] ----
__global__ void cvt_x(const float* __restrict__ x, half_t* __restrict__ xh) {
    const int row = blockIdx.x;             // row = b*256 + t
    const int b = row >> 8, t = row & 255;
    const int o = threadIdx.x * 4;
    const float4 v = *(const float4*)(x + (size_t)row * ND + o);
    const size_t d = ((size_t)t * NB + b) * ND + o;
    h4 hh;
    hh.x = (half_t)v.x; hh.y = (half_t)v.y;
    hh.z = (half_t)v.z; hh.w = (half_t)v.w;
    *(h4*)(xh + d) = hh;
}

// ---- one-time weight pack (r14-proven): region (combo,jp,gt,kh): [ki][lane][8] ----
__global__ void transpose_pack(const float* __restrict__ fw_Wx,
                               const float* __restrict__ fw_Wh,
                               const float* __restrict__ bw_Wx,
                               const float* __restrict__ bw_Wh,
                               half_t* __restrict__ WT) {
    const int z = blockIdx.z;
    const int combo = z >> 1;
    const int half  = z & 1;               // 0 -> Wx, 1 -> Wh (== kh)
    const int layer = combo >> 1, dirb = combo & 1;
    const float* src = half ? (dirb ? bw_Wh : fw_Wh) : (dirb ? bw_Wx : fw_Wx);
    src += (size_t)layer * ND * G4;
    const int n0 = blockIdx.x * 64, k0 = blockIdx.y * 64;
    __shared__ float tile[64][65];
    const int t = threadIdx.x;             // 256 threads
    #pragma unroll
    for (int it = 0; it < 4; ++it) {
        const int kr = it * 16 + (t >> 4);
        const int nc = (t & 15) * 4;
        const float4 v = *(const float4*)(src + (size_t)(k0 + kr) * G4 + n0 + nc);
        tile[kr][nc + 0] = v.x; tile[kr][nc + 1] = v.y;
        tile[kr][nc + 2] = v.z; tile[kr][nc + 3] = v.w;
    }
    __syncthreads();
    #pragma unroll
    for (int it = 0; it < 4; ++it) {
        const int nr = it * 16 + (t >> 4);
        const int kc = (t & 15) * 4;
        h4 hv;
        hv.x = (half_t)tile[kc + 0][nr];
        hv.y = (half_t)tile[kc + 1][nr];
        hv.z = (half_t)tile[kc + 2][nr];
        hv.w = (half_t)tile[kc + 3][nr];
        const int n = n0 + nr;                 // 0..4095
        const int kr1 = k0 + kc;               // 0..1023 within this kh
        const int gt = n >> 10, j = n & 1023;
        const int jp = j >> 4, l15j = j & 15;
        const int ki = kr1 >> 5, g2 = (kr1 >> 3) & 3, e0 = kr1 & 7;
        const int lane2 = g2 * 16 + l15j;
        const size_t r = (((size_t)combo * 64 + jp) * 4 + gt) * 2 + half;
        *(h4*)(WT + r * WREG + (size_t)ki * 512 + lane2 * 8 + e0) = hv;
    }
}

// ---- sc1 store (write-through past the non-coherent L2) ----
__device__ __forceinline__ void store_h2(half_t* p, half_t a, half_t b) {
    union { half_t h[2]; unsigned int u; } v;
    v.h[0] = a; v.h[1] = b;
    __hip_atomic_store((unsigned int*)p, v.u,
                       __ATOMIC_RELAXED, __HIP_MEMORY_SCOPE_AGENT);
}

// ---- persistent scan: 256 blocks x 512 thr; 8 waves = (gate, khalf) [r14 skeleton]
// A single fp16 plane, double-buffered LDS chunks, 1 barrier per chunk.
// hring: [slot 0..NT][combo][B][H] fp16 — monotonic, write-once addresses
__global__ __launch_bounds__(512, 2) void lstm_persistent(
        const half_t* __restrict__ xh,
        const int* __restrict__ lengths,
        const float* __restrict__ fw_b, const float* __restrict__ bw_b,
        const half_t* __restrict__ WT,
        half_t* __restrict__ hring,
        float* __restrict__ out,
        int* __restrict__ bar) {
    const int bid = blockIdx.x;
    const int c  = (bid & 7) >> 1;                 // combo (XCD-pair-local)
    const int jp = ((bid >> 3) << 1) | (bid & 1);  // 0..63
    const int layer = c >> 1, dir = c & 1;
    const int tid = threadIdx.x;
    const int wv = tid >> 6, lane = tid & 63;
    const int gt = wv & 3, kh = wv >> 2;           // gate, K-half
    const int l15 = lane & 15, g = lane >> 4;
    const int j0 = jp * 16;

    // staging role: 256 threads per kh-half; 4 threads per row (32 halves each)
    const int shf  = tid >> 8;                     // which K-half this thread stages
    const int srow = (tid & 255) >> 2;             // 0..63 (batch row)
    const int sks  = (tid & 3) * 32;               // 32-half segment within 128

    __shared__ half_t alds[2][2][64][136];         // [buf][kh][row][128+8]  69.6 KB
    __shared__ float glds[4][2][NB][17];           // padded: conflict-free  34.8 KB
    __shared__ float c_lds[NB][17];
    __shared__ float h_lds[NB][17];
    __shared__ float bias_lds[4][16];
    __shared__ int   len_lds[NB];

    for (int e = tid; e < NB * 16; e += 512) {
        c_lds[e >> 4][e & 15] = 0.f;
        h_lds[e >> 4][e & 15] = 0.f;
    }
    if (tid < NB) len_lds[tid] = lengths[tid];
    if (tid < 64) {
        const int gg = tid >> 4, jj = tid & 15;
        const float* bs = dir ? bw_b : fw_b;
        bias_lds[gg][jj] = bs[(size_t)layer * G4 + gg * NH + j0 + jj];
    }

    // ---- weight preload, pinned ONCE into AGPRs (r14-proven construct) ----
    v8h w[32];
    {
        const half_t* wp = WT + ((((size_t)c * 64 + jp) * 4 + gt) * 2 + kh) * WREG
                         + (size_t)lane * 8;
        #pragma unroll
        for (int ki = 0; ki < 32; ++ki) w[ki] = *(const v8h*)(wp + (size_t)ki * 512);
    }
    #pragma unroll
    for (int ki = 0; ki < 32; ++ki) asm volatile("" : "+a"(w[ki]));
    __syncthreads();

    const int id128 = layer * 64 + jp;
    int* gcnt = bar + ((size_t)dir * 8 + (id128 >> 4)) * 16;
    int* root = bar + 256 + dir * 16;
    int* rel  = bar + 320 + dir * 16;

    for (int s = 0; s <= NT; ++s) {
        const bool active = (layer == 0) ? (s < NT) : (s >= 1);
        const int u = (layer == 0) ? s : (s - 1);

        // per-thread staging source (uniform per shf-group), row stride 1024
        const half_t* bsrc = nullptr;
        if (active) {
            if (shf == 0) {
                if (layer == 0) {
                    const int t = dir ? (NT - 1 - u) : u;
                    bsrc = xh + (size_t)t * NB * ND;
                } else {
                    bsrc = hring + ((size_t)s * 4 + dir) * HPLANE;
                }
            } else {
                bsrc = hring + ((size_t)u * 4 + c) * HPLANE;
            }
        }

        v4f acc[4];
        #pragma unroll
        for (int m = 0; m < 4; ++m) acc[m] = (v4f){0.f, 0.f, 0.f, 0.f};

        v8h sh[4];                         // staged regs: 32 halves (one chunk seg)
        if (active) {
            const size_t o0 = (size_t)srow * 1024 + sks;       // chunk 0
            #pragma unroll
            for (int i = 0; i < 4; ++i) sh[i] = *(const v8h*)(bsrc + o0 + i * 8);
        }

        #pragma unroll
        for (int ci = 0; ci < 8; ++ci) {
            if (active) {
                #pragma unroll
                for (int i = 0; i < 4; ++i)
                    *(v8h*)&alds[ci & 1][shf][srow][sks + i * 8] = sh[i];
                if (ci < 7) {              // issue prefetch before the barrier
                    const size_t o = (size_t)srow * 1024 + (ci + 1) * 128 + sks;
                    #pragma unroll
                    for (int i = 0; i < 4; ++i) sh[i] = *(const v8h*)(bsrc + o + i * 8);
                }
            }
            __syncthreads();               // chunk ci visible; prior reads drained
            if (active) {
                #pragma unroll
                for (int ki = 0; ki < 4; ++ki) {
                    #pragma unroll
                    for (int m = 0; m < 4; ++m) {
                        v8h ah = *(const v8h*)&alds[ci & 1][kh][m * 16 + l15]
                                              [ki * 32 + g * 8];
                        acc[m] = __builtin_amdgcn_mfma_f32_16x16x32_f16(
                                     ah, w[ci * 4 + ki], acc[m], 0, 0, 0);
                    }
                }
            }
        }

        if (active) {
            // C/D: col = l15 (jj), row-in-Mtile = g*4 + r (batch)
            #pragma unroll
            for (int m = 0; m < 4; ++m)
                #pragma unroll
                for (int r = 0; r < 4; ++r)
                    glds[gt][kh][m * 16 + g * 4 + r][l15] = acc[m][r];
        }
        __syncthreads();

        if (active) {
            const int b = tid >> 3, jj0 = (tid & 7) * 2;
            float hpair[2];
            #pragma unroll
            for (int k2 = 0; k2 < 2; ++k2) {
                const int jj = jj0 + k2;
                const float iv = glds[0][0][b][jj] + glds[0][1][b][jj] + bias_lds[0][jj];
                const float fv = glds[1][0][b][jj] + glds[1][1][b][jj] + bias_lds[1][jj];
                const float gv = glds[2][0][b][jj] + glds[2][1][b][jj] + bias_lds[2][jj];
                const float ov = glds[3][0][b][jj] + glds[3][1][b][jj] + bias_lds[3][jj];
                const float cold = c_lds[b][jj];
                const float hold = h_lds[b][jj];
                const float si = 1.f / (1.f + expf(-iv));
                const float sf = 1.f / (1.f + expf(-fv));
                const float so = 1.f / (1.f + expf(-ov));
                const float cn = sf * cold + si * tanhf(gv);
                const float hn = so * tanhf(cn);
                const bool valid = len_lds[b] > u;   // un-reversed mask (reference quirk)
                const float c2 = valid ? cn : cold;
                const float h2 = valid ? hn : hold;
                c_lds[b][jj] = c2;
                h_lds[b][jj] = h2;
                hpair[k2] = h2;
                if (layer == 1) {
                    const int tout = dir ? (NT - 1 - u) : u;
                    __builtin_nontemporal_store(
                        h2, &out[((size_t)b * NT + tout) * (2 * NH) + dir * NH + j0 + jj]);
                    if (u == NT - 1)
                        __builtin_nontemporal_store(
                            h2, &out[(size_t)NB * NT * (2 * NH) + (size_t)b * (2 * NH)
                                     + dir * NH + j0 + jj]);
                }
            }
            // h handoff into fresh ring slot u+1 (single fp16 plane, sc1 store)
            half_t* hb2 = hring + ((size_t)(u + 1) * 4 + c) * HPLANE
                        + (size_t)b * NH + j0 + jj0;
            store_h2(hb2, (half_t)hpair[0], (half_t)hpair[1]);
        }

        // ---- per-direction barrier: relaxed atomics, no fences ----
        const int phase = s + 1;
        __syncthreads();                    // vmcnt(0): sc1 h-stores visible
        if (tid == 0) {
            const int a = __hip_atomic_fetch_add(gcnt, 1, __ATOMIC_RELAXED,
                                                 __HIP_MEMORY_SCOPE_AGENT) + 1;
            if (a == phase * 16) {
                const int rr = __hip_atomic_fetch_add(root, 1, __ATOMIC_RELAXED,
                                                      __HIP_MEMORY_SCOPE_AGENT) + 1;
                if (rr == phase * 8)
                    __hip_atomic_store(rel, phase, __ATOMIC_RELAXED,
                                       __HIP_MEMORY_SCOPE_AGENT);
            }
            while (__hip_atomic_load(rel, __ATOMIC_RELAXED,
                                     __HIP_MEMORY_SCOPE_AGENT) < phase)
                __builtin_amdgcn_s_sleep(2);
        }
        __syncthreads();
    }
}

extern "C" void kernel_launch(void* const* d_in, const int* in_sizes, int n_in,
                              void* d_out, int out_size, void* d_ws, size_t ws_size,
                              hipStream_t stream) {
    (void)in_sizes; (void)n_in; (void)out_size; (void)ws_size;
    const float* x     = (const float*)d_in[0];
    const int*   len   = (const int*)d_in[1];
    const float* fw_Wx = (const float*)d_in[2];
    const float* fw_Wh = (const float*)d_in[3];
    const float* fw_b  = (const float*)d_in[4];
    const float* bw_Wx = (const float*)d_in[5];
    const float* bw_Wh = (const float*)d_in[6];
    const float* bw_b  = (const float*)d_in[7];
    float* out = (float*)d_out;

    char* ws = (char*)d_ws;
    size_t off = 0;
    half_t* WT = (half_t*)(ws + off); off += (size_t)2048 * WREG * 2;   // 64 MB
    half_t* xh = (half_t*)(ws + off); off += XPLANE * 2;                // 32 MB
    int* bar = (int*)(ws + off); off += 4096;                           // 4 KB
    half_t* hring = (half_t*)(ws + off);                                // 134.7 MB

    // zero barrier counters + ring slot 0 (4 combos x 128 KB = 512 KB)
    hipMemsetAsync(bar, 0, 4096 + (size_t)4 * HPLANE * 2, stream);

    cvt_x<<<NB * NT, 256, 0, stream>>>(x, xh);

    dim3 tg(G4 / 64, ND / 64, 8);
    transpose_pack<<<tg, 256, 0, stream>>>(fw_Wx, fw_Wh, bw_Wx, bw_Wh, WT);

    void* args[] = {(void*)&xh, (void*)&len, (void*)&fw_b, (void*)&bw_b,
                    (void*)&WT, (void*)&hring, (void*)&out, (void*)&bar};
    hipLaunchCooperativeKernel((void*)lstm_persistent, dim3(256), dim3(512),
                               args, 0, stream);
}

// Round 17
// 2463.961 us; speedup vs baseline: 8.0301x; 1.0045x over previous
//
#include <hip/hip_runtime.h>

#define NB 64
#define NT 256
#define ND 1024
#define NH 1024
#define G4 4096

typedef _Float16 half_t;
typedef half_t v8h __attribute__((ext_vector_type(8)));
typedef half_t h4  __attribute__((ext_vector_type(4)));
typedef float  v4f __attribute__((ext_vector_type(4)));

#define XPLANE ((size_t)NB * NT * ND)
#define HPLANE ((size_t)NB * NH)       // halves per (slot, combo) — single plane
#define WREG   16384                   // halves per (combo,jp,gt,kh) region (32 KB)

// ---- one-time: x (f32, B,T,D) -> fp16 single plane, transposed to [t][b][d] ----
__global__ void cvt_x(const float* __restrict__ x, half_t* __restrict__ xh) {
    const int row = blockIdx.x;             // row = b*256 + t
    const int b = row >> 8, t = row & 255;
    const int o = threadIdx.x * 4;
    const float4 v = *(const float4*)(x + (size_t)row * ND + o);
    const size_t d = ((size_t)t * NB + b) * ND + o;
    h4 hh;
    hh.x = (half_t)v.x; hh.y = (half_t)v.y;
    hh.z = (half_t)v.z; hh.w = (half_t)v.w;
    *(h4*)(xh + d) = hh;
}

// ---- one-time weight pack (r14-proven): region (combo,jp,gt,kh): [ki][lane][8] ----
__global__ void transpose_pack(const float* __restrict__ fw_Wx,
                               const float* __restrict__ fw_Wh,
                               const float* __restrict__ bw_Wx,
                               const float* __restrict__ bw_Wh,
                               half_t* __restrict__ WT) {
    const int z = blockIdx.z;
    const int combo = z >> 1;
    const int half  = z & 1;               // 0 -> Wx, 1 -> Wh (== kh)
    const int layer = combo >> 1, dirb = combo & 1;
    const float* src = half ? (dirb ? bw_Wh : fw_Wh) : (dirb ? bw_Wx : fw_Wx);
    src += (size_t)layer * ND * G4;
    const int n0 = blockIdx.x * 64, k0 = blockIdx.y * 64;
    __shared__ float tile[64][65];
    const int t = threadIdx.x;             // 256 threads
    #pragma unroll
    for (int it = 0; it < 4; ++it) {
        const int kr = it * 16 + (t >> 4);
        const int nc = (t & 15) * 4;
        const float4 v = *(const float4*)(src + (size_t)(k0 + kr) * G4 + n0 + nc);
        tile[kr][nc + 0] = v.x; tile[kr][nc + 1] = v.y;
        tile[kr][nc + 2] = v.z; tile[kr][nc + 3] = v.w;
    }
    __syncthreads();
    #pragma unroll
    for (int it = 0; it < 4; ++it) {
        const int nr = it * 16 + (t >> 4);
        const int kc = (t & 15) * 4;
        h4 hv;
        hv.x = (half_t)tile[kc + 0][nr];
        hv.y = (half_t)tile[kc + 1][nr];
        hv.z = (half_t)tile[kc + 2][nr];
        hv.w = (half_t)tile[kc + 3][nr];
        const int n = n0 + nr;                 // 0..4095
        const int kr1 = k0 + kc;               // 0..1023 within this kh
        const int gt = n >> 10, j = n & 1023;
        const int jp = j >> 4, l15j = j & 15;
        const int ki = kr1 >> 5, g2 = (kr1 >> 3) & 3, e0 = kr1 & 7;
        const int lane2 = g2 * 16 + l15j;
        const size_t r = (((size_t)combo * 64 + jp) * 4 + gt) * 2 + half;
        *(h4*)(WT + r * WREG + (size_t)ki * 512 + lane2 * 8 + e0) = hv;
    }
}

// ---- sc1 store (write-through past the non-coherent L2) ----
__device__ __forceinline__ void store_h2(half_t* p, half_t a, half_t b) {
    union { half_t h[2]; unsigned int u; } v;
    v.h[0] = a; v.h[1] = b;
    __hip_atomic_store((unsigned int*)p, v.u,
                       __ATOMIC_RELAXED, __HIP_MEMORY_SCOPE_AGENT);
}

// ---- persistent scan: 256 blocks x 512 thr; 8 waves = (gate, khalf)
// A single fp16 plane, double-buffered LDS chunks (XOR-swizzled), 1 barrier/chunk.
// hring: [slot 0..NT][combo][B][H] fp16 — monotonic, write-once addresses
__global__ __launch_bounds__(512, 2) void lstm_persistent(
        const half_t* __restrict__ xh,
        const int* __restrict__ lengths,
        const float* __restrict__ fw_b, const float* __restrict__ bw_b,
        const half_t* __restrict__ WT,
        half_t* __restrict__ hring,
        float* __restrict__ out,
        int* __restrict__ bar) {
    const int bid = blockIdx.x;
    const int c  = (bid & 7) >> 1;                 // combo (XCD-pair-local)
    const int jp = ((bid >> 3) << 1) | (bid & 1);  // 0..63
    const int layer = c >> 1, dir = c & 1;
    const int tid = threadIdx.x;
    const int wv = tid >> 6, lane = tid & 63;
    const int gt = wv & 3, kh = wv >> 2;           // gate, K-half
    const int l15 = lane & 15, g = lane >> 4;
    const int j0 = jp * 16;

    // staging role: 256 threads per kh-half; 4 threads per row (32 halves each)
    const int shf  = tid >> 8;                     // which K-half this thread stages
    const int srow = (tid & 255) >> 2;             // 0..63 (batch row)
    const int sks  = (tid & 3) * 32;               // 32-half segment within 128
    const int sswz = (srow & 7) << 3;              // write-side XOR (8-half units)
    const int rswz = (l15 & 7) << 3;               // read-side XOR (row&7 == l15&7)

    __shared__ half_t alds[2][2][64][128];         // [buf][kh][row][128]  64 KB
    __shared__ float glds[4][2][NB][17];           // 34.8 KB
    __shared__ float c_lds[NB][17];
    __shared__ float h_lds[NB][17];
    __shared__ float bias_lds[4][16];
    __shared__ int   len_lds[NB];

    for (int e = tid; e < NB * 16; e += 512) {
        c_lds[e >> 4][e & 15] = 0.f;
        h_lds[e >> 4][e & 15] = 0.f;
    }
    if (tid < NB) len_lds[tid] = lengths[tid];
    if (tid < 64) {
        const int gg = tid >> 4, jj = tid & 15;
        const float* bs = dir ? bw_b : fw_b;
        bias_lds[gg][jj] = bs[(size_t)layer * G4 + gg * NH + j0 + jj];
    }

    // ---- weight preload, pinned ONCE into AGPRs (r14-proven construct) ----
    v8h w[32];
    {
        const half_t* wp = WT + ((((size_t)c * 64 + jp) * 4 + gt) * 2 + kh) * WREG
                         + (size_t)lane * 8;
        #pragma unroll
        for (int ki = 0; ki < 32; ++ki) w[ki] = *(const v8h*)(wp + (size_t)ki * 512);
    }
    #pragma unroll
    for (int ki = 0; ki < 32; ++ki) asm volatile("" : "+a"(w[ki]));
    __syncthreads();

    const int id128 = layer * 64 + jp;
    int* gcnt = bar + ((size_t)dir * 8 + (id128 >> 4)) * 16;
    int* root = bar + 256 + dir * 16;
    int* rel  = bar + 320 + dir * 16;

    for (int s = 0; s <= NT; ++s) {
        const bool active = (layer == 0) ? (s < NT) : (s >= 1);
        const int u = (layer == 0) ? s : (s - 1);

        // per-thread staging source (uniform per shf-group), row stride 1024
        const half_t* bsrc = nullptr;
        if (active) {
            if (shf == 0) {
                if (layer == 0) {
                    const int t = dir ? (NT - 1 - u) : u;
                    bsrc = xh + (size_t)t * NB * ND;
                } else {
                    bsrc = hring + ((size_t)s * 4 + dir) * HPLANE;
                }
            } else {
                bsrc = hring + ((size_t)u * 4 + c) * HPLANE;
            }
        }

        v4f acc[4];
        #pragma unroll
        for (int m = 0; m < 4; ++m) acc[m] = (v4f){0.f, 0.f, 0.f, 0.f};

        v8h sh[4];                         // staged regs: 32 halves (one chunk seg)
        if (active) {
            const size_t o0 = (size_t)srow * 1024 + sks;       // chunk 0
            #pragma unroll
            for (int i = 0; i < 4; ++i) sh[i] = *(const v8h*)(bsrc + o0 + i * 8);
        }

        #pragma unroll
        for (int ci = 0; ci < 8; ++ci) {
            if (active) {
                #pragma unroll
                for (int i = 0; i < 4; ++i)
                    *(v8h*)&alds[ci & 1][shf][srow][(sks + i * 8) ^ sswz] = sh[i];
                if (ci < 7) {              // issue prefetch before the barrier
                    const size_t o = (size_t)srow * 1024 + (ci + 1) * 128 + sks;
                    #pragma unroll
                    for (int i = 0; i < 4; ++i) sh[i] = *(const v8h*)(bsrc + o + i * 8);
                }
            }
            __syncthreads();               // chunk ci visible; prior reads drained
            if (active) {
                #pragma unroll
                for (int ki = 0; ki < 4; ++ki) {
                    #pragma unroll
                    for (int m = 0; m < 4; ++m) {
                        v8h ah = *(const v8h*)&alds[ci & 1][kh][m * 16 + l15]
                                              [(ki * 32 + g * 8) ^ rswz];
                        acc[m] = __builtin_amdgcn_mfma_f32_16x16x32_f16(
                                     ah, w[ci * 4 + ki], acc[m], 0, 0, 0);
                    }
                }
            }
        }

        if (active) {
            // C/D: col = l15 (jj), row-in-Mtile = g*4 + r (batch)
            #pragma unroll
            for (int m = 0; m < 4; ++m)
                #pragma unroll
                for (int r = 0; r < 4; ++r)
                    glds[gt][kh][m * 16 + g * 4 + r][l15] = acc[m][r];
        }
        __syncthreads();

        if (active) {
            const int b = tid >> 3, jj0 = (tid & 7) * 2;
            float hpair[2];
            #pragma unroll
            for (int k2 = 0; k2 < 2; ++k2) {
                const int jj = jj0 + k2;
                const float iv = glds[0][0][b][jj] + glds[0][1][b][jj] + bias_lds[0][jj];
                const float fv = glds[1][0][b][jj] + glds[1][1][b][jj] + bias_lds[1][jj];
                const float gv = glds[2][0][b][jj] + glds[2][1][b][jj] + bias_lds[2][jj];
                const float ov = glds[3][0][b][jj] + glds[3][1][b][jj] + bias_lds[3][jj];
                const float cold = c_lds[b][jj];
                const float hold = h_lds[b][jj];
                const float si = 1.f / (1.f + expf(-iv));
                const float sf = 1.f / (1.f + expf(-fv));
                const float so = 1.f / (1.f + expf(-ov));
                const float cn = sf * cold + si * tanhf(gv);
                const float hn = so * tanhf(cn);
                const bool valid = len_lds[b] > u;   // un-reversed mask (reference quirk)
                const float c2 = valid ? cn : cold;
                const float h2 = valid ? hn : hold;
                c_lds[b][jj] = c2;
                h_lds[b][jj] = h2;
                hpair[k2] = h2;
                if (layer == 1) {
                    const int tout = dir ? (NT - 1 - u) : u;
                    __builtin_nontemporal_store(
                        h2, &out[((size_t)b * NT + tout) * (2 * NH) + dir * NH + j0 + jj]);
                    if (u == NT - 1)
                        __builtin_nontemporal_store(
                            h2, &out[(size_t)NB * NT * (2 * NH) + (size_t)b * (2 * NH)
                                     + dir * NH + j0 + jj]);
                }
            }
            // h handoff into fresh ring slot u+1 (single fp16 plane, sc1 store)
            half_t* hb2 = hring + ((size_t)(u + 1) * 4 + c) * HPLANE
                        + (size_t)b * NH + j0 + jj0;
            store_h2(hb2, (half_t)hpair[0], (half_t)hpair[1]);
        }

        // ---- per-direction barrier: relaxed atomics, no fences ----
        const int phase = s + 1;
        __syncthreads();                    // vmcnt(0): sc1 h-stores visible
        if (tid == 0) {
            const int a = __hip_atomic_fetch_add(gcnt, 1, __ATOMIC_RELAXED,
                                                 __HIP_MEMORY_SCOPE_AGENT) + 1;
            if (a == phase * 16) {
                const int rr = __hip_atomic_fetch_add(root, 1, __ATOMIC_RELAXED,
                                                      __HIP_MEMORY_SCOPE_AGENT) + 1;
                if (rr == phase * 8)
                    __hip_atomic_store(rel, phase, __ATOMIC_RELAXED,
                                       __HIP_MEMORY_SCOPE_AGENT);
            }
            while (__hip_atomic_load(rel, __ATOMIC_RELAXED,
                                     __HIP_MEMORY_SCOPE_AGENT) < phase)
                __builtin_amdgcn_s_sleep(1);
        }
        __syncthreads();
    }
}

extern "C" void kernel_launch(void* const* d_in, const int* in_sizes, int n_in,
                              void* d_out, int out_size, void* d_ws, size_t ws_size,
                              hipStream_t stream) {
    (void)in_sizes; (void)n_in; (void)out_size; (void)ws_size;
    const float* x     = (const float*)d_in[0];
    const int*   len   = (const int*)d_in[1];
    const float* fw_Wx = (const float*)d_in[2];
    const float* fw_Wh = (const float*)d_in[3];
    const float* fw_b  = (const float*)d_in[4];
    const float* bw_Wx = (const float*)d_in[5];
    const float* bw_Wh = (const float*)d_in[6];
    const float* bw_b  = (const float*)d_in[7];
    float* out = (float*)d_out;

    char* ws = (char*)d_ws;
    size_t off = 0;
    half_t* WT = (half_t*)(ws + off); off += (size_t)2048 * WREG * 2;   // 64 MB
    half_t* xh = (half_t*)(ws + off); off += XPLANE * 2;                // 32 MB
    int* bar = (int*)(ws + off); off += 4096;                           // 4 KB
    half_t* hring = (half_t*)(ws + off);                                // 134.7 MB

    // zero barrier counters + ring slot 0 (4 combos x 128 KB = 512 KB)
    hipMemsetAsync(bar, 0, 4096 + (size_t)4 * HPLANE * 2, stream);

    cvt_x<<<NB * NT, 256, 0, stream>>>(x, xh);

    dim3 tg(G4 / 64, ND / 64, 8);
    transpose_pack<<<tg, 256, 0, stream>>>(fw_Wx, fw_Wh, bw_Wx, bw_Wh, WT);

    void* args[] = {(void*)&xh, (void*)&len, (void*)&fw_b, (void*)&bw_b,
                    (void*)&WT, (void*)&hring, (void*)&out, (void*)&bar};
    hipLaunchCooperativeKernel((void*)lstm_persistent, dim3(256), dim3(512),
                               args, 0, stream);
}